// Round 10
// baseline (325.913 us; speedup 1.0000x reference)
//
#include <hip/hip_runtime.h>
#include <hip/hip_fp16.h>

typedef _Float16 f16;
typedef _Float16 f16x8 __attribute__((ext_vector_type(8)));
typedef __fp16 h16x2 __attribute__((ext_vector_type(2)));
typedef float f32x4 __attribute__((ext_vector_type(4)));
typedef float f32x16 __attribute__((ext_vector_type(16)));

#define LOG2E 1.4426950408889634f
#define NSL 0.2f

// ---------------- Kernel 1: graph -> j-major transposed bitmask (+ init M2e) ----------------
__global__ __launch_bounds__(256) void k_mask(const int* __restrict__ graph,
                                              unsigned int* __restrict__ maskJ,
                                              unsigned int* __restrict__ M2e) {
    if (blockIdx.x == 0 && threadIdx.x < 8) M2e[threadIdx.x] = 0x007FFFFFu;  // enc(-inf)
    __shared__ unsigned long long bal[4][64];
    int w = threadIdx.x >> 6;
    int lane = threadIdx.x & 63;
    int gw = blockIdx.x * 4 + w;
    int ti = gw & 63, tj = gw >> 6;
    int i0 = ti * 64, j0 = tj * 64;
    #pragma unroll 8
    for (int k = 0; k < 64; k++) {
        int g = graph[(j0 + k) * 4096 + i0 + lane];
        unsigned long long b = __ballot(g > 0);
        if (lane == 0) bal[w][k] = b;
    }
    __syncthreads();
    unsigned long long word = 0;
    #pragma unroll 8
    for (int k = 0; k < 64; k++) {
        word |= ((bal[w][k] >> lane) & 1ull) << k;
    }
    int jw = j0 >> 5;
    maskJ[(size_t)jw * 4096 + i0 + lane]       = (unsigned int)word;
    maskJ[(size_t)(jw + 1) * 4096 + i0 + lane] = (unsigned int)(word >> 32);
}

// ---------------- Kernel 2 (fused prep): xcvt + swizzled weight transposes ----------------
__device__ void dev_transpose_sw(const float* __restrict__ in, f16* __restrict__ out,
                                 int C, int S, int bxx, int byy, int tid) {
    __shared__ float tile[32][33];
    int tx = tid & 31, ty = tid >> 5;
    int c0 = bxx * 32, r0 = byy * 32;
    for (int rr = ty; rr < 32; rr += 8)
        tile[rr][tx] = in[(r0 + rr) * C + c0 + tx];
    __syncthreads();
    for (int rr = ty; rr < 32; rr += 8) {
        int m = r0 + tx, f = c0 + rr;
        out[(size_t)((m >> 4) * S + f) * 16 + (m & 15)] = (f16)tile[tx][rr];
    }
}

__global__ __launch_bounds__(256) void k_pre(const float* __restrict__ x,
                                             f16* __restrict__ xh2,
                                             const float* __restrict__ W,
                                             f16* __restrict__ Wht2,
                                             const float* __restrict__ Wr,
                                             f16* __restrict__ Wrt2) {
    int bx = blockIdx.x;
    int tid = threadIdx.x;
    if (bx < 512) {
        int id = bx * 256 + tid;   // 131072
        int row = id & 4095, kt = id >> 12;
        const float4* xs = (const float4*)(x + (size_t)row * 512 + kt * 16);
        float4 u0 = xs[0], u1 = xs[1], u2 = xs[2], u3 = xs[3];
        union { int4 a[2]; h16x2 p[8]; } px;
        px.p[0] = __builtin_amdgcn_cvt_pkrtz(u0.x, u0.y);
        px.p[1] = __builtin_amdgcn_cvt_pkrtz(u0.z, u0.w);
        px.p[2] = __builtin_amdgcn_cvt_pkrtz(u1.x, u1.y);
        px.p[3] = __builtin_amdgcn_cvt_pkrtz(u1.z, u1.w);
        px.p[4] = __builtin_amdgcn_cvt_pkrtz(u2.x, u2.y);
        px.p[5] = __builtin_amdgcn_cvt_pkrtz(u2.z, u2.w);
        px.p[6] = __builtin_amdgcn_cvt_pkrtz(u3.x, u3.y);
        px.p[7] = __builtin_amdgcn_cvt_pkrtz(u3.z, u3.w);
        int4* d = (int4*)(xh2 + ((size_t)kt * 4096 + row) * 16);
        d[0] = px.a[0]; d[1] = px.a[1];
    } else if (bx < 1024) {
        int id = bx - 512;                       // W -> Wht2
        dev_transpose_sw(W, Wht2, 128, 128, id & 3, id >> 2, tid);
    } else {
        int id = bx - 1024;                      // Wr -> Wrt2
        dev_transpose_sw(Wr, Wrt2, 1024, 1024, id & 31, id >> 5, tid);
    }
}

// ---------------- Kernel 3: hbT2 + fused a2/b2 + per-head max ----------------
__global__ __launch_bounds__(256, 4) void k_gemm_h(const f16* __restrict__ xh2,
                                                   const f16* __restrict__ Wht2,
                                                   f16* __restrict__ hbT2,
                                                   const float* __restrict__ wi,
                                                   const float* __restrict__ wj,
                                                   float* __restrict__ a2,
                                                   float* __restrict__ b2,
                                                   unsigned int* __restrict__ M2e) {
    __shared__ float swi[128], swj[128];
    __shared__ float pwa[4][32], pwb[4][32];
    int bx = blockIdx.x;
    int h = bx & 7, jb = bx >> 3;        // 128 j-tiles of 32
    int j0 = jb * 32;
    int tid = threadIdx.x;
    int w = tid >> 6, lane = tid & 63;
    int ln = lane & 15, q = lane >> 4;
    if (tid < 128) { swi[tid] = wi[h * 128 + tid]; swj[tid] = wj[h * 128 + tid]; }
    __syncthreads();

    int ko = (q & 1) * 8;
    const f16* pa = Wht2 + ((size_t)(h * 512) * 8 + (size_t)(q >> 1) * 128 + w * 32 + ln) * 16 + ko;
    const f16* pb = xh2 + ((size_t)(q >> 1) * 4096 + j0 + ln) * 16 + ko;

    f32x4 acc00 = {}, acc01 = {}, acc10 = {}, acc11 = {};

    f16x8 ra0 = *(const f16x8*)(pa);
    f16x8 ra1 = *(const f16x8*)(pa + 256);
    f16x8 rb0 = *(const f16x8*)(pb);
    f16x8 rb1 = *(const f16x8*)(pb + 256);

    for (int kk = 0; kk < 8; kk++) {
        f16x8 sa0 = *(const f16x8*)(pa + 4096);
        f16x8 sa1 = *(const f16x8*)(pa + 4096 + 256);
        f16x8 sb0 = *(const f16x8*)(pb + 131072);
        f16x8 sb1 = *(const f16x8*)(pb + 131072 + 256);
        acc00 = __builtin_amdgcn_mfma_f32_16x16x32_f16(ra0, rb0, acc00, 0, 0, 0);
        acc01 = __builtin_amdgcn_mfma_f32_16x16x32_f16(ra0, rb1, acc01, 0, 0, 0);
        acc10 = __builtin_amdgcn_mfma_f32_16x16x32_f16(ra1, rb0, acc10, 0, 0, 0);
        acc11 = __builtin_amdgcn_mfma_f32_16x16x32_f16(ra1, rb1, acc11, 0, 0, 0);
        pa += 8192; pb += 262144;
        ra0 = *(const f16x8*)(pa);
        ra1 = *(const f16x8*)(pa + 256);
        rb0 = *(const f16x8*)(pb);
        rb1 = *(const f16x8*)(pb + 256);
        acc00 = __builtin_amdgcn_mfma_f32_16x16x32_f16(sa0, sb0, acc00, 0, 0, 0);
        acc01 = __builtin_amdgcn_mfma_f32_16x16x32_f16(sa0, sb1, acc01, 0, 0, 0);
        acc10 = __builtin_amdgcn_mfma_f32_16x16x32_f16(sa1, sb0, acc10, 0, 0, 0);
        acc11 = __builtin_amdgcn_mfma_f32_16x16x32_f16(sa1, sb1, acc11, 0, 0, 0);
    }

    size_t hb = (size_t)h * 524288 + (size_t)(j0 >> 4) * 2048;
    #pragma unroll
    for (int r = 0; r < 4; r++) {
        int f0 = w * 32 + q * 4 + r;
        hbT2[hb + f0 * 16 + ln]                 = (f16)acc00[r];
        hbT2[hb + 2048 + f0 * 16 + ln]          = (f16)acc01[r];
        hbT2[hb + (f0 + 16) * 16 + ln]          = (f16)acc10[r];
        hbT2[hb + 2048 + (f0 + 16) * 16 + ln]   = (f16)acc11[r];
    }

    float pa0 = 0.f, pb0 = 0.f, pa1 = 0.f, pb1 = 0.f;
    #pragma unroll
    for (int r = 0; r < 4; r++) {
        int f0 = w * 32 + q * 4 + r;
        float w0 = swi[f0], jv0 = swj[f0];
        float w1 = swi[f0 + 16], jv1 = swj[f0 + 16];
        pa0 += acc00[r] * w0 + acc10[r] * w1;
        pb0 += acc00[r] * jv0 + acc10[r] * jv1;
        pa1 += acc01[r] * w0 + acc11[r] * w1;
        pb1 += acc01[r] * jv0 + acc11[r] * jv1;
    }
    pa0 += __shfl_xor(pa0, 16); pa0 += __shfl_xor(pa0, 32);
    pb0 += __shfl_xor(pb0, 16); pb0 += __shfl_xor(pb0, 32);
    pa1 += __shfl_xor(pa1, 16); pa1 += __shfl_xor(pa1, 32);
    pb1 += __shfl_xor(pb1, 16); pb1 += __shfl_xor(pb1, 32);
    if (lane < 16) {
        pwa[w][ln] = pa0;      pwb[w][ln] = pb0;
        pwa[w][16 + ln] = pa1; pwb[w][16 + ln] = pb1;
    }
    __syncthreads();
    if (tid < 32) {
        int jj = tid;
        float pav = (pwa[0][jj] + pwa[1][jj]) + (pwa[2][jj] + pwa[3][jj]);
        float pbv = (pwb[0][jj] + pwb[1][jj]) + (pwb[2][jj] + pwb[3][jj]);
        a2[h * 4096 + j0 + jj] = pav * LOG2E;
        float bb = pbv * LOG2E;
        b2[h * 4096 + j0 + jj] = bb;
        float m = bb;
        m = fmaxf(m, __shfl_xor(m, 1, 32));
        m = fmaxf(m, __shfl_xor(m, 2, 32));
        m = fmaxf(m, __shfl_xor(m, 4, 32));
        m = fmaxf(m, __shfl_xor(m, 8, 32));
        m = fmaxf(m, __shfl_xor(m, 16, 32));
        if (jj == 0) {
            unsigned u = __float_as_uint(m);
            unsigned enc = (u & 0x80000000u) ? ~u : (u | 0x80000000u);
            atomicMax(&M2e[h], enc);
        }
    }
}

// ---------------- Kernel 5: exp tables ----------------
__global__ __launch_bounds__(256) void k_prep(const float* __restrict__ a2,
                                              const float* __restrict__ b2,
                                              const unsigned int* __restrict__ M2e,
                                              float* __restrict__ ABpre,
                                              float* __restrict__ Bpre) {
    int id = blockIdx.x * 256 + threadIdx.x;   // 32768
    int h = id >> 12;
    unsigned enc = M2e[h];
    unsigned u = (enc & 0x80000000u) ? (enc & 0x7FFFFFFFu) : ~enc;
    float M2 = __uint_as_float(u);
    float av = a2[id];
    float t = av + M2;
    float m2 = fmaxf(t, NSL * t);
    ((float2*)ABpre)[id] = make_float2(exp2f(av - m2), exp2f(NSL * av - m2));
    float bv = b2[id];
    ((float2*)Bpre)[id] = make_float2(exp2f(bv), exp2f(NSL * bv));
}

// ---------------- Kernel 6 helpers ----------------
#define PGEN(af, mw, shv, bpq)                                                   \
    {                                                                            \
        float4 q0 = (bpq)[0], q1 = (bpq)[1], q2 = (bpq)[2], q3 = (bpq)[3];       \
        unsigned m8 = (mw) >> (shv);                                             \
        float e0, e1;                                                            \
        e0 = fmaxf(Ai * q0.x, Ai2 * q0.y); e1 = fmaxf(Ai * q0.z, Ai2 * q0.w);    \
        e0 = (m8 & 1u) ? e0 : 0.f;  e1 = (m8 & 2u) ? e1 : 0.f;                   \
        dsum += e0 + e1; af.p[0] = __builtin_amdgcn_cvt_pkrtz(e0, e1);           \
        e0 = fmaxf(Ai * q1.x, Ai2 * q1.y); e1 = fmaxf(Ai * q1.z, Ai2 * q1.w);    \
        e0 = (m8 & 4u) ? e0 : 0.f;  e1 = (m8 & 8u) ? e1 : 0.f;                   \
        dsum += e0 + e1; af.p[1] = __builtin_amdgcn_cvt_pkrtz(e0, e1);           \
        e0 = fmaxf(Ai * q2.x, Ai2 * q2.y); e1 = fmaxf(Ai * q2.z, Ai2 * q2.w);    \
        e0 = (m8 & 16u) ? e0 : 0.f; e1 = (m8 & 32u) ? e1 : 0.f;                  \
        dsum += e0 + e1; af.p[2] = __builtin_amdgcn_cvt_pkrtz(e0, e1);           \
        e0 = fmaxf(Ai * q3.x, Ai2 * q3.y); e1 = fmaxf(Ai * q3.z, Ai2 * q3.w);    \
        e0 = (m8 & 64u) ? e0 : 0.f; e1 = (m8 & 128u) ? e1 : 0.f;                 \
        dsum += e0 + e1; af.p[3] = __builtin_amdgcn_cvt_pkrtz(e0, e1);           \
    }

#define LOADSET(s0, s1, s2, s3, ptr)                 \
    s0 = *(const f16x8*)(ptr);                       \
    s1 = *(const f16x8*)((ptr) + 512);               \
    s2 = *(const f16x8*)((ptr) + 1024);              \
    s3 = *(const f16x8*)((ptr) + 1536);

#define BODY(s0, s1, s2, s3, mwv, shv, tidx)                                     \
    {                                                                            \
        union { f16x8 v; h16x2 p[4]; } af;                                       \
        const float4* bpq = (const float4*)(bp0 + (tidx) * 32);                  \
        PGEN(af, mwv, shv, bpq);                                                 \
        acc0 = __builtin_amdgcn_mfma_f32_32x32x16_f16(af.v, s0, acc0, 0, 0, 0);  \
        acc1 = __builtin_amdgcn_mfma_f32_32x32x16_f16(af.v, s1, acc1, 0, 0, 0);  \
        acc2 = __builtin_amdgcn_mfma_f32_32x32x16_f16(af.v, s2, acc2, 0, 0, 0);  \
        acc3 = __builtin_amdgcn_mfma_f32_32x32x16_f16(af.v, s3, acc3, 0, 0, 0);  \
    }

// ---------------- Kernel 6: main — distance-3 software pipeline, 4 static frag sets ----------------
// Block = (h=bx&7 XCD-pinned, 32-i strip). Wave w = j-quarter (1024 j = 64 tiles of 16 j).
// Load for tile t+3 issues 3 bodies (~360 cyc work) before use -> covers ~200 cyc L2 latency.
__global__ __launch_bounds__(256, 3) void k_main(const f16* __restrict__ xh2,
                                                 const f16* __restrict__ hbT2,
                                                 const f16* __restrict__ Wrt2,
                                                 const unsigned int* __restrict__ maskJ,
                                                 const float* __restrict__ ABpre,
                                                 const float* __restrict__ Bpre,
                                                 const float* __restrict__ bias,
                                                 float* __restrict__ out) {
    __shared__ float xred[2][64 * 68];   // 34816 B
    __shared__ float dred[128];

    int bx = blockIdx.x;
    int h = bx & 7, it = bx >> 3;
    int i0 = it * 32;
    int tid = threadIdx.x;
    int w = tid >> 6, lane = tid & 63;
    int l31 = lane & 31, half = lane >> 5;
    int i = i0 + l31;

    float2 Av = *(const float2*)(ABpre + 2 * (h * 4096 + i));
    float Ai = Av.x, Ai2 = Av.y;

    f32x16 acc0 = {}, acc1 = {}, acc2 = {}, acc3 = {};
    float dsum = 0.f;

    int J0 = w * 1024;
    const f16* bb = hbT2 + (size_t)h * 524288 + ((size_t)(J0 >> 4) * 128 + l31) * 16 + half * 8;
    const float* bp0 = Bpre + 2 * (h * 4096 + J0) + half * 16;
    const unsigned int* mrow = maskJ + (size_t)(J0 >> 5) * 4096 + i;

    int sh0 = half << 3;            // even-t mask shift
    int sh1 = 16 + (half << 3);     // odd-t mask shift

    // 4 statically-named fragment sets (distance-3 pipeline)
    f16x8 g00, g01, g02, g03;
    f16x8 g10, g11, g12, g13;
    f16x8 g20, g21, g22, g23;
    f16x8 g30, g31, g32, g33;
    LOADSET(g00, g01, g02, g03, bb);
    LOADSET(g10, g11, g12, g13, bb + 2048);
    LOADSET(g20, g21, g22, g23, bb + 4096);
    const f16* pld = bb + 3 * 2048;

    for (int tt = 0; tt < 16; tt++) {
        int t0 = tt * 4;
        unsigned mw0 = mrow[(size_t)(tt * 2) * 4096];
        unsigned mw1 = mrow[(size_t)(tt * 2 + 1) * 4096];

        LOADSET(g30, g31, g32, g33, pld); pld += 2048;
        BODY(g00, g01, g02, g03, mw0, sh0, t0);

        LOADSET(g00, g01, g02, g03, pld); pld += 2048;
        BODY(g10, g11, g12, g13, mw0, sh1, t0 + 1);

        LOADSET(g10, g11, g12, g13, pld); pld += 2048;
        BODY(g20, g21, g22, g23, mw1, sh0, t0 + 2);

        LOADSET(g20, g21, g22, g23, pld); pld += 2048;   // last-iter overrun stays in workspace
        BODY(g30, g31, g32, g33, mw1, sh1, t0 + 3);
    }

    // ---- denominator: combine j-halves in-wave, then cross-wave via LDS ----
    dsum += __shfl(dsum, lane ^ 32);
    if (lane < 32) dred[w * 32 + l31] = dsum;
    __syncthreads();
    {
        #pragma unroll
        for (int r = 0; r < 16; r++) {
            int row = (r & 3) + 8 * (r >> 2) + 4 * half;
            float s = dred[row] + dred[32 + row] + dred[64 + row] + dred[96 + row];
            float inv = 1.0f / s;
            acc0[r] *= inv; acc1[r] *= inv; acc2[r] *= inv; acc3[r] *= inv;
        }
    }

    // ---- residual: acc += x @ Wr[:, h-slice]; k-quarter per wave, direct fragment loads ----
    {
        #pragma unroll
        for (int kt = 0; kt < 8; kt++) {
            int ktt = w * 8 + kt;
            f16x8 ax = *(const f16x8*)(xh2 + ((size_t)ktt * 4096 + i) * 16 + half * 8);
            const f16* wb = Wrt2 + ((size_t)ktt * 1024 + h * 128 + l31) * 16 + half * 8;
            acc0 = __builtin_amdgcn_mfma_f32_32x32x16_f16(ax, *(const f16x8*)(wb), acc0, 0, 0, 0);
            acc1 = __builtin_amdgcn_mfma_f32_32x32x16_f16(ax, *(const f16x8*)(wb + 512), acc1, 0, 0, 0);
            acc2 = __builtin_amdgcn_mfma_f32_32x32x16_f16(ax, *(const f16x8*)(wb + 1024), acc2, 0, 0, 0);
            acc3 = __builtin_amdgcn_mfma_f32_32x32x16_f16(ax, *(const f16x8*)(wb + 1536), acc3, 0, 0, 0);
        }
    }

    // ---- cross-wave O reduction: (w2,w3)->(w0,w1), then w1->w0; w0 stores ----
    union uu { f32x16 v; f32x4 q[4]; };
    uu u0, u1, u2, u3;
    u0.v = acc0; u1.v = acc1; u2.v = acc2; u3.v = acc3;
    __syncthreads();   // dred reads done
    if (w >= 2) {
        float* dp = xred[w - 2] + lane * 68;
        #pragma unroll
        for (int k4 = 0; k4 < 4; k4++) {
            *(f32x4*)(dp + k4 * 4)      = u0.q[k4];
            *(f32x4*)(dp + 16 + k4 * 4) = u1.q[k4];
            *(f32x4*)(dp + 32 + k4 * 4) = u2.q[k4];
            *(f32x4*)(dp + 48 + k4 * 4) = u3.q[k4];
        }
    }
    __syncthreads();
    if (w < 2) {
        const float* dp = xred[w] + lane * 68;
        #pragma unroll
        for (int k4 = 0; k4 < 4; k4++) {
            u0.q[k4] += *(const f32x4*)(dp + k4 * 4);
            u1.q[k4] += *(const f32x4*)(dp + 16 + k4 * 4);
            u2.q[k4] += *(const f32x4*)(dp + 32 + k4 * 4);
            u3.q[k4] += *(const f32x4*)(dp + 48 + k4 * 4);
        }
    }
    __syncthreads();
    if (w == 1) {
        float* dp = xred[0] + lane * 68;
        #pragma unroll
        for (int k4 = 0; k4 < 4; k4++) {
            *(f32x4*)(dp + k4 * 4)      = u0.q[k4];
            *(f32x4*)(dp + 16 + k4 * 4) = u1.q[k4];
            *(f32x4*)(dp + 32 + k4 * 4) = u2.q[k4];
            *(f32x4*)(dp + 48 + k4 * 4) = u3.q[k4];
        }
    }
    __syncthreads();
    if (w == 0) {
        const float* dp = xred[0] + lane * 68;
        #pragma unroll
        for (int k4 = 0; k4 < 4; k4++) {
            u0.q[k4] += *(const f32x4*)(dp + k4 * 4);
            u1.q[k4] += *(const f32x4*)(dp + 16 + k4 * 4);
            u2.q[k4] += *(const f32x4*)(dp + 32 + k4 * 4);
            u3.q[k4] += *(const f32x4*)(dp + 48 + k4 * 4);
        }
        float bv0 = bias[h * 128 + l31];
        float bv1 = bias[h * 128 + 32 + l31];
        float bv2 = bias[h * 128 + 64 + l31];
        float bv3 = bias[h * 128 + 96 + l31];
        #pragma unroll
        for (int r = 0; r < 16; r++) {
            int row = i0 + (r & 3) + 8 * (r >> 2) + 4 * half;
            float* op = out + (size_t)row * 1024 + h * 128 + l31;
            op[0]  = u0.v[r] + bv0;
            op[32] = u1.v[r] + bv1;
            op[64] = u2.v[r] + bv2;
            op[96] = u3.v[r] + bv3;
        }
    }
}

extern "C" void kernel_launch(void* const* d_in, const int* in_sizes, int n_in,
                              void* d_out, int out_size, void* d_ws, size_t ws_size,
                              hipStream_t stream) {
    (void)in_sizes; (void)n_in; (void)out_size; (void)ws_size;
    const float* x     = (const float*)d_in[0];
    const int*   graph = (const int*)d_in[1];
    const float* W     = (const float*)d_in[2];
    const float* wi    = (const float*)d_in[3];
    const float* wj    = (const float*)d_in[4];
    const float* Wr    = (const float*)d_in[5];
    const float* bias  = (const float*)d_in[6];
    float* out = (float*)d_out;

    char* ws = (char*)d_ws;
    unsigned int* maskJ = (unsigned int*)ws;              // 2 MB  [128 jw][4096 i]
    f16* hbT2  = (f16*)(ws + (2u << 20));                 // 8 MB  [8][(j>>4)*128+f][j&15]
    f16* Wht2  = (f16*)(ws + (10u << 20));                // 1 MB  swizzled
    f16* Wrt2  = (f16*)(ws + (11u << 20));                // 1 MB  swizzled
    f16* xh2   = (f16*)(ws + (12u << 20));                // 4 MB  [32][4096][16] swizzled
    float* a2    = (float*)(ws + (16u << 20));            // 128 KB
    float* b2    = a2 + 8 * 4096;
    float* ABpre = b2 + 8 * 4096;
    float* Bpre  = ABpre + 2 * 8 * 4096;
    unsigned int* M2e = (unsigned int*)(Bpre + 2 * 8 * 4096);

    hipLaunchKernelGGL(k_mask, dim3(1024), dim3(256), 0, stream, graph, maskJ, M2e);
    hipLaunchKernelGGL(k_pre, dim3(1536), dim3(256), 0, stream, x, xh2, W, Wht2, Wr, Wrt2);
    hipLaunchKernelGGL(k_gemm_h, dim3(1024), dim3(256), 0, stream, xh2, Wht2, hbT2,
                       wi, wj, a2, b2, M2e);
    hipLaunchKernelGGL(k_prep, dim3(128), dim3(256), 0, stream, a2, b2, M2e, ABpre, Bpre);
    hipLaunchKernelGGL(k_main, dim3(1024), dim3(256), 0, stream, xh2, hbT2, Wrt2, maskJ,
                       ABpre, Bpre, bias, out);
}

// Round 11
// 247.665 us; speedup vs baseline: 1.3159x; 1.3159x over previous
//
#include <hip/hip_runtime.h>
#include <hip/hip_fp16.h>

typedef _Float16 f16;
typedef _Float16 f16x8 __attribute__((ext_vector_type(8)));
typedef __fp16 h16x2 __attribute__((ext_vector_type(2)));
typedef float f32x4 __attribute__((ext_vector_type(4)));
typedef float f32x16 __attribute__((ext_vector_type(16)));

#define LOG2E 1.4426950408889634f
#define NSL 0.2f

// ---------------- Kernel 1: graph -> j-major transposed bitmask (+ init M2e) ----------------
__global__ __launch_bounds__(256) void k_mask(const int* __restrict__ graph,
                                              unsigned int* __restrict__ maskJ,
                                              unsigned int* __restrict__ M2e) {
    if (blockIdx.x == 0 && threadIdx.x < 8) M2e[threadIdx.x] = 0x007FFFFFu;  // enc(-inf)
    __shared__ unsigned long long bal[4][64];
    int w = threadIdx.x >> 6;
    int lane = threadIdx.x & 63;
    int gw = blockIdx.x * 4 + w;
    int ti = gw & 63, tj = gw >> 6;
    int i0 = ti * 64, j0 = tj * 64;
    #pragma unroll 8
    for (int k = 0; k < 64; k++) {
        int g = graph[(j0 + k) * 4096 + i0 + lane];
        unsigned long long b = __ballot(g > 0);
        if (lane == 0) bal[w][k] = b;
    }
    __syncthreads();
    unsigned long long word = 0;
    #pragma unroll 8
    for (int k = 0; k < 64; k++) {
        word |= ((bal[w][k] >> lane) & 1ull) << k;
    }
    int jw = j0 >> 5;
    maskJ[(size_t)jw * 4096 + i0 + lane]       = (unsigned int)word;
    maskJ[(size_t)(jw + 1) * 4096 + i0 + lane] = (unsigned int)(word >> 32);
}

// ---------------- Kernel 2 (fused prep): xcvt + swizzled weight transposes ----------------
__device__ void dev_transpose_sw(const float* __restrict__ in, f16* __restrict__ out,
                                 int C, int S, int bxx, int byy, int tid) {
    __shared__ float tile[32][33];
    int tx = tid & 31, ty = tid >> 5;
    int c0 = bxx * 32, r0 = byy * 32;
    for (int rr = ty; rr < 32; rr += 8)
        tile[rr][tx] = in[(r0 + rr) * C + c0 + tx];
    __syncthreads();
    for (int rr = ty; rr < 32; rr += 8) {
        int m = r0 + tx, f = c0 + rr;
        out[(size_t)((m >> 4) * S + f) * 16 + (m & 15)] = (f16)tile[tx][rr];
    }
}

__global__ __launch_bounds__(256) void k_pre(const float* __restrict__ x,
                                             f16* __restrict__ xh2,
                                             const float* __restrict__ W,
                                             f16* __restrict__ Wht2,
                                             const float* __restrict__ Wr,
                                             f16* __restrict__ Wrt2) {
    int bx = blockIdx.x;
    int tid = threadIdx.x;
    if (bx < 512) {
        int id = bx * 256 + tid;   // 131072
        int row = id & 4095, kt = id >> 12;
        const float4* xs = (const float4*)(x + (size_t)row * 512 + kt * 16);
        float4 u0 = xs[0], u1 = xs[1], u2 = xs[2], u3 = xs[3];
        union { int4 a[2]; h16x2 p[8]; } px;
        px.p[0] = __builtin_amdgcn_cvt_pkrtz(u0.x, u0.y);
        px.p[1] = __builtin_amdgcn_cvt_pkrtz(u0.z, u0.w);
        px.p[2] = __builtin_amdgcn_cvt_pkrtz(u1.x, u1.y);
        px.p[3] = __builtin_amdgcn_cvt_pkrtz(u1.z, u1.w);
        px.p[4] = __builtin_amdgcn_cvt_pkrtz(u2.x, u2.y);
        px.p[5] = __builtin_amdgcn_cvt_pkrtz(u2.z, u2.w);
        px.p[6] = __builtin_amdgcn_cvt_pkrtz(u3.x, u3.y);
        px.p[7] = __builtin_amdgcn_cvt_pkrtz(u3.z, u3.w);
        int4* d = (int4*)(xh2 + ((size_t)kt * 4096 + row) * 16);
        d[0] = px.a[0]; d[1] = px.a[1];
    } else if (bx < 1024) {
        int id = bx - 512;                       // W -> Wht2
        dev_transpose_sw(W, Wht2, 128, 128, id & 3, id >> 2, tid);
    } else {
        int id = bx - 1024;                      // Wr -> Wrt2
        dev_transpose_sw(Wr, Wrt2, 1024, 1024, id & 31, id >> 5, tid);
    }
}

// ---------------- Kernel 3: hbT2 + fused a2/b2 + per-head max ----------------
__global__ __launch_bounds__(256, 4) void k_gemm_h(const f16* __restrict__ xh2,
                                                   const f16* __restrict__ Wht2,
                                                   f16* __restrict__ hbT2,
                                                   const float* __restrict__ wi,
                                                   const float* __restrict__ wj,
                                                   float* __restrict__ a2,
                                                   float* __restrict__ b2,
                                                   unsigned int* __restrict__ M2e) {
    __shared__ float swi[128], swj[128];
    __shared__ float pwa[4][32], pwb[4][32];
    int bx = blockIdx.x;
    int h = bx & 7, jb = bx >> 3;        // 128 j-tiles of 32
    int j0 = jb * 32;
    int tid = threadIdx.x;
    int w = tid >> 6, lane = tid & 63;
    int ln = lane & 15, q = lane >> 4;
    if (tid < 128) { swi[tid] = wi[h * 128 + tid]; swj[tid] = wj[h * 128 + tid]; }
    __syncthreads();

    int ko = (q & 1) * 8;
    const f16* pa = Wht2 + ((size_t)(h * 512) * 8 + (size_t)(q >> 1) * 128 + w * 32 + ln) * 16 + ko;
    const f16* pb = xh2 + ((size_t)(q >> 1) * 4096 + j0 + ln) * 16 + ko;

    f32x4 acc00 = {}, acc01 = {}, acc10 = {}, acc11 = {};

    f16x8 ra0 = *(const f16x8*)(pa);
    f16x8 ra1 = *(const f16x8*)(pa + 256);
    f16x8 rb0 = *(const f16x8*)(pb);
    f16x8 rb1 = *(const f16x8*)(pb + 256);

    for (int kk = 0; kk < 8; kk++) {
        f16x8 sa0 = *(const f16x8*)(pa + 4096);
        f16x8 sa1 = *(const f16x8*)(pa + 4096 + 256);
        f16x8 sb0 = *(const f16x8*)(pb + 131072);
        f16x8 sb1 = *(const f16x8*)(pb + 131072 + 256);
        acc00 = __builtin_amdgcn_mfma_f32_16x16x32_f16(ra0, rb0, acc00, 0, 0, 0);
        acc01 = __builtin_amdgcn_mfma_f32_16x16x32_f16(ra0, rb1, acc01, 0, 0, 0);
        acc10 = __builtin_amdgcn_mfma_f32_16x16x32_f16(ra1, rb0, acc10, 0, 0, 0);
        acc11 = __builtin_amdgcn_mfma_f32_16x16x32_f16(ra1, rb1, acc11, 0, 0, 0);
        pa += 8192; pb += 262144;
        ra0 = *(const f16x8*)(pa);
        ra1 = *(const f16x8*)(pa + 256);
        rb0 = *(const f16x8*)(pb);
        rb1 = *(const f16x8*)(pb + 256);
        acc00 = __builtin_amdgcn_mfma_f32_16x16x32_f16(sa0, sb0, acc00, 0, 0, 0);
        acc01 = __builtin_amdgcn_mfma_f32_16x16x32_f16(sa0, sb1, acc01, 0, 0, 0);
        acc10 = __builtin_amdgcn_mfma_f32_16x16x32_f16(sa1, sb0, acc10, 0, 0, 0);
        acc11 = __builtin_amdgcn_mfma_f32_16x16x32_f16(sa1, sb1, acc11, 0, 0, 0);
    }

    size_t hb = (size_t)h * 524288 + (size_t)(j0 >> 4) * 2048;
    #pragma unroll
    for (int r = 0; r < 4; r++) {
        int f0 = w * 32 + q * 4 + r;
        hbT2[hb + f0 * 16 + ln]                 = (f16)acc00[r];
        hbT2[hb + 2048 + f0 * 16 + ln]          = (f16)acc01[r];
        hbT2[hb + (f0 + 16) * 16 + ln]          = (f16)acc10[r];
        hbT2[hb + 2048 + (f0 + 16) * 16 + ln]   = (f16)acc11[r];
    }

    float pa0 = 0.f, pb0 = 0.f, pa1 = 0.f, pb1 = 0.f;
    #pragma unroll
    for (int r = 0; r < 4; r++) {
        int f0 = w * 32 + q * 4 + r;
        float w0 = swi[f0], jv0 = swj[f0];
        float w1 = swi[f0 + 16], jv1 = swj[f0 + 16];
        pa0 += acc00[r] * w0 + acc10[r] * w1;
        pb0 += acc00[r] * jv0 + acc10[r] * jv1;
        pa1 += acc01[r] * w0 + acc11[r] * w1;
        pb1 += acc01[r] * jv0 + acc11[r] * jv1;
    }
    pa0 += __shfl_xor(pa0, 16); pa0 += __shfl_xor(pa0, 32);
    pb0 += __shfl_xor(pb0, 16); pb0 += __shfl_xor(pb0, 32);
    pa1 += __shfl_xor(pa1, 16); pa1 += __shfl_xor(pa1, 32);
    pb1 += __shfl_xor(pb1, 16); pb1 += __shfl_xor(pb1, 32);
    if (lane < 16) {
        pwa[w][ln] = pa0;      pwb[w][ln] = pb0;
        pwa[w][16 + ln] = pa1; pwb[w][16 + ln] = pb1;
    }
    __syncthreads();
    if (tid < 32) {
        int jj = tid;
        float pav = (pwa[0][jj] + pwa[1][jj]) + (pwa[2][jj] + pwa[3][jj]);
        float pbv = (pwb[0][jj] + pwb[1][jj]) + (pwb[2][jj] + pwb[3][jj]);
        a2[h * 4096 + j0 + jj] = pav * LOG2E;
        float bb = pbv * LOG2E;
        b2[h * 4096 + j0 + jj] = bb;
        float m = bb;
        m = fmaxf(m, __shfl_xor(m, 1, 32));
        m = fmaxf(m, __shfl_xor(m, 2, 32));
        m = fmaxf(m, __shfl_xor(m, 4, 32));
        m = fmaxf(m, __shfl_xor(m, 8, 32));
        m = fmaxf(m, __shfl_xor(m, 16, 32));
        if (jj == 0) {
            unsigned u = __float_as_uint(m);
            unsigned enc = (u & 0x80000000u) ? ~u : (u | 0x80000000u);
            atomicMax(&M2e[h], enc);
        }
    }
}

// ---------------- Kernel 5: exp tables ----------------
__global__ __launch_bounds__(256) void k_prep(const float* __restrict__ a2,
                                              const float* __restrict__ b2,
                                              const unsigned int* __restrict__ M2e,
                                              float* __restrict__ ABpre,
                                              float* __restrict__ Bpre) {
    int id = blockIdx.x * 256 + threadIdx.x;   // 32768
    int h = id >> 12;
    unsigned enc = M2e[h];
    unsigned u = (enc & 0x80000000u) ? (enc & 0x7FFFFFFFu) : ~enc;
    float M2 = __uint_as_float(u);
    float av = a2[id];
    float t = av + M2;
    float m2 = fmaxf(t, NSL * t);
    ((float2*)ABpre)[id] = make_float2(exp2f(av - m2), exp2f(NSL * av - m2));
    float bv = b2[id];
    ((float2*)Bpre)[id] = make_float2(exp2f(bv), exp2f(NSL * bv));
}

// ---------------- Kernel 6 helpers ----------------
#define PGEN(af, mw, shv, bpq)                                                   \
    {                                                                            \
        float4 q0 = (bpq)[0], q1 = (bpq)[1], q2 = (bpq)[2], q3 = (bpq)[3];       \
        unsigned m8 = (mw) >> (shv);                                             \
        float e0, e1;                                                            \
        e0 = fmaxf(Ai * q0.x, Ai2 * q0.y); e1 = fmaxf(Ai * q0.z, Ai2 * q0.w);    \
        e0 = (m8 & 1u) ? e0 : 0.f;  e1 = (m8 & 2u) ? e1 : 0.f;                   \
        dsum += e0 + e1; af.p[0] = __builtin_amdgcn_cvt_pkrtz(e0, e1);           \
        e0 = fmaxf(Ai * q1.x, Ai2 * q1.y); e1 = fmaxf(Ai * q1.z, Ai2 * q1.w);    \
        e0 = (m8 & 4u) ? e0 : 0.f;  e1 = (m8 & 8u) ? e1 : 0.f;                   \
        dsum += e0 + e1; af.p[1] = __builtin_amdgcn_cvt_pkrtz(e0, e1);           \
        e0 = fmaxf(Ai * q2.x, Ai2 * q2.y); e1 = fmaxf(Ai * q2.z, Ai2 * q2.w);    \
        e0 = (m8 & 16u) ? e0 : 0.f; e1 = (m8 & 32u) ? e1 : 0.f;                  \
        dsum += e0 + e1; af.p[2] = __builtin_amdgcn_cvt_pkrtz(e0, e1);           \
        e0 = fmaxf(Ai * q3.x, Ai2 * q3.y); e1 = fmaxf(Ai * q3.z, Ai2 * q3.w);    \
        e0 = (m8 & 64u) ? e0 : 0.f; e1 = (m8 & 128u) ? e1 : 0.f;                 \
        dsum += e0 + e1; af.p[3] = __builtin_amdgcn_cvt_pkrtz(e0, e1);           \
    }

// one-acc-at-a-time LDS put / add-in (scoped unions keep peak VGPR low)
#define PUTACC(dp, off, accv)                                                    \
    {                                                                            \
        union { f32x16 v; f32x4 q[4]; } t; t.v = (accv);                         \
        *(f32x4*)((dp) + (off))      = t.q[0];                                   \
        *(f32x4*)((dp) + (off) + 4)  = t.q[1];                                   \
        *(f32x4*)((dp) + (off) + 8)  = t.q[2];                                   \
        *(f32x4*)((dp) + (off) + 12) = t.q[3];                                   \
    }

#define ADDACC(dp, off, accv)                                                    \
    {                                                                            \
        union { f32x16 v; f32x4 q[4]; } t; t.v = (accv);                         \
        t.q[0] += *(const f32x4*)((dp) + (off));                                 \
        t.q[1] += *(const f32x4*)((dp) + (off) + 4);                             \
        t.q[2] += *(const f32x4*)((dp) + (off) + 8);                             \
        t.q[3] += *(const f32x4*)((dp) + (off) + 12);                            \
        (accv) = t.v;                                                            \
    }

// ---------------- Kernel 6: main — R9 loop + 4 waves/SIMD (low-VGPR epilogue) ----------------
// Block = (h=bx&7 XCD-pinned, 32-i strip). Wave w = j-quarter. Static dbuf distance-1.
__global__ __launch_bounds__(256, 4) void k_main(const f16* __restrict__ xh2,
                                                 const f16* __restrict__ hbT2,
                                                 const f16* __restrict__ Wrt2,
                                                 const unsigned int* __restrict__ maskJ,
                                                 const float* __restrict__ ABpre,
                                                 const float* __restrict__ Bpre,
                                                 const float* __restrict__ bias,
                                                 float* __restrict__ out) {
    __shared__ float xred[2][64 * 68];   // 34816 B
    __shared__ float dred[128];

    int bx = blockIdx.x;
    int h = bx & 7, it = bx >> 3;
    int i0 = it * 32;
    int tid = threadIdx.x;
    int w = tid >> 6, lane = tid & 63;
    int l31 = lane & 31, half = lane >> 5;
    int i = i0 + l31;

    float2 Av = *(const float2*)(ABpre + 2 * (h * 4096 + i));
    float Ai = Av.x, Ai2 = Av.y;

    f32x16 acc0 = {}, acc1 = {}, acc2 = {}, acc3 = {};
    float dsum = 0.f;

    int J0 = w * 1024;
    const f16* bb = hbT2 + (size_t)h * 524288 + ((size_t)(J0 >> 4) * 128 + l31) * 16 + half * 8;
    const float* bp0 = Bpre + 2 * (h * 4096 + J0) + half * 16;
    const unsigned int* mrow = maskJ + (size_t)(J0 >> 5) * 4096 + i;

    // statically-named double buffers (4 frags = 128 f)
    f16x8 fa0 = *(const f16x8*)(bb);
    f16x8 fa1 = *(const f16x8*)(bb + 512);
    f16x8 fa2 = *(const f16x8*)(bb + 1024);
    f16x8 fa3 = *(const f16x8*)(bb + 1536);

    for (int tt = 0; tt < 32; tt++) {
        int t0 = tt * 2;
        unsigned mw = mrow[(size_t)tt * 4096];   // one u32 covers both bodies

        // prefetch t0+1 into b-buffers
        const f16* s1 = bb + (size_t)(t0 + 1) * 2048;
        f16x8 fb0 = *(const f16x8*)(s1);
        f16x8 fb1 = *(const f16x8*)(s1 + 512);
        f16x8 fb2 = *(const f16x8*)(s1 + 1024);
        f16x8 fb3 = *(const f16x8*)(s1 + 1536);

        // body even t0 (uses a-buffers)
        {
            union { f16x8 v; h16x2 p[4]; } af;
            const float4* bpq = (const float4*)(bp0 + t0 * 32);
            PGEN(af, mw, (half << 3), bpq);
            acc0 = __builtin_amdgcn_mfma_f32_32x32x16_f16(af.v, fa0, acc0, 0, 0, 0);
            acc1 = __builtin_amdgcn_mfma_f32_32x32x16_f16(af.v, fa1, acc1, 0, 0, 0);
            acc2 = __builtin_amdgcn_mfma_f32_32x32x16_f16(af.v, fa2, acc2, 0, 0, 0);
            acc3 = __builtin_amdgcn_mfma_f32_32x32x16_f16(af.v, fa3, acc3, 0, 0, 0);
        }

        // prefetch t0+2 into a-buffers (last-iter overrun stays inside workspace; never used)
        const f16* s2 = bb + (size_t)(t0 + 2) * 2048;
        fa0 = *(const f16x8*)(s2);
        fa1 = *(const f16x8*)(s2 + 512);
        fa2 = *(const f16x8*)(s2 + 1024);
        fa3 = *(const f16x8*)(s2 + 1536);

        // body odd t0+1 (uses b-buffers)
        {
            union { f16x8 v; h16x2 p[4]; } af;
            const float4* bpq = (const float4*)(bp0 + (t0 + 1) * 32);
            PGEN(af, mw, (16 + (half << 3)), bpq);
            acc0 = __builtin_amdgcn_mfma_f32_32x32x16_f16(af.v, fb0, acc0, 0, 0, 0);
            acc1 = __builtin_amdgcn_mfma_f32_32x32x16_f16(af.v, fb1, acc1, 0, 0, 0);
            acc2 = __builtin_amdgcn_mfma_f32_32x32x16_f16(af.v, fb2, acc2, 0, 0, 0);
            acc3 = __builtin_amdgcn_mfma_f32_32x32x16_f16(af.v, fb3, acc3, 0, 0, 0);
        }
    }

    // ---- denominator: combine j-halves in-wave, then cross-wave via LDS ----
    dsum += __shfl(dsum, lane ^ 32);
    if (lane < 32) dred[w * 32 + l31] = dsum;
    __syncthreads();
    {
        #pragma unroll
        for (int r = 0; r < 16; r++) {
            int row = (r & 3) + 8 * (r >> 2) + 4 * half;
            float s = dred[row] + dred[32 + row] + dred[64 + row] + dred[96 + row];
            float inv = 1.0f / s;
            acc0[r] *= inv; acc1[r] *= inv; acc2[r] *= inv; acc3[r] *= inv;
        }
    }

    // ---- residual: acc += x @ Wr[:, h-slice]; k-quarter per wave, direct fragment loads ----
    {
        #pragma unroll
        for (int kt = 0; kt < 8; kt++) {
            int ktt = w * 8 + kt;
            f16x8 ax = *(const f16x8*)(xh2 + ((size_t)ktt * 4096 + i) * 16 + half * 8);
            const f16* wb = Wrt2 + ((size_t)ktt * 1024 + h * 128 + l31) * 16 + half * 8;
            acc0 = __builtin_amdgcn_mfma_f32_32x32x16_f16(ax, *(const f16x8*)(wb), acc0, 0, 0, 0);
            acc1 = __builtin_amdgcn_mfma_f32_32x32x16_f16(ax, *(const f16x8*)(wb + 512), acc1, 0, 0, 0);
            acc2 = __builtin_amdgcn_mfma_f32_32x32x16_f16(ax, *(const f16x8*)(wb + 1024), acc2, 0, 0, 0);
            acc3 = __builtin_amdgcn_mfma_f32_32x32x16_f16(ax, *(const f16x8*)(wb + 1536), acc3, 0, 0, 0);
        }
    }

    // ---- cross-wave O reduction, one accumulator at a time (low peak VGPR) ----
    __syncthreads();   // dred reads done
    if (w >= 2) {
        float* dp = xred[w - 2] + lane * 68;
        PUTACC(dp, 0, acc0);
        PUTACC(dp, 16, acc1);
        PUTACC(dp, 32, acc2);
        PUTACC(dp, 48, acc3);
    }
    __syncthreads();
    if (w < 2) {
        const float* dp = xred[w] + lane * 68;
        ADDACC(dp, 0, acc0);
        ADDACC(dp, 16, acc1);
        ADDACC(dp, 32, acc2);
        ADDACC(dp, 48, acc3);
    }
    __syncthreads();
    if (w == 1) {
        float* dp = xred[0] + lane * 68;
        PUTACC(dp, 0, acc0);
        PUTACC(dp, 16, acc1);
        PUTACC(dp, 32, acc2);
        PUTACC(dp, 48, acc3);
    }
    __syncthreads();
    if (w == 0) {
        const float* dp = xred[0] + lane * 68;
        ADDACC(dp, 0, acc0);
        ADDACC(dp, 16, acc1);
        ADDACC(dp, 32, acc2);
        ADDACC(dp, 48, acc3);
        #pragma unroll
        for (int n = 0; n < 4; n++) {
            union { f32x16 v; f32x4 q[4]; } t;
            t.v = (n == 0) ? acc0 : (n == 1) ? acc1 : (n == 2) ? acc2 : acc3;
            int col = h * 128 + n * 32 + l31;
            float bv = bias[col];
            #pragma unroll
            for (int r = 0; r < 16; r++) {
                int row = i0 + (r & 3) + 8 * (r >> 2) + 4 * half;
                out[(size_t)row * 1024 + col] = t.v[r] + bv;
            }
        }
    }
}

extern "C" void kernel_launch(void* const* d_in, const int* in_sizes, int n_in,
                              void* d_out, int out_size, void* d_ws, size_t ws_size,
                              hipStream_t stream) {
    (void)in_sizes; (void)n_in; (void)out_size; (void)ws_size;
    const float* x     = (const float*)d_in[0];
    const int*   graph = (const int*)d_in[1];
    const float* W     = (const float*)d_in[2];
    const float* wi    = (const float*)d_in[3];
    const float* wj    = (const float*)d_in[4];
    const float* Wr    = (const float*)d_in[5];
    const float* bias  = (const float*)d_in[6];
    float* out = (float*)d_out;

    char* ws = (char*)d_ws;
    unsigned int* maskJ = (unsigned int*)ws;              // 2 MB  [128 jw][4096 i]
    f16* hbT2  = (f16*)(ws + (2u << 20));                 // 8 MB  [8][(j>>4)*128+f][j&15]
    f16* Wht2  = (f16*)(ws + (10u << 20));                // 1 MB  swizzled
    f16* Wrt2  = (f16*)(ws + (11u << 20));                // 1 MB  swizzled
    f16* xh2   = (f16*)(ws + (12u << 20));                // 4 MB  [32][4096][16] swizzled
    float* a2    = (float*)(ws + (16u << 20));            // 128 KB
    float* b2    = a2 + 8 * 4096;
    float* ABpre = b2 + 8 * 4096;
    float* Bpre  = ABpre + 2 * 8 * 4096;
    unsigned int* M2e = (unsigned int*)(Bpre + 2 * 8 * 4096);

    hipLaunchKernelGGL(k_mask, dim3(1024), dim3(256), 0, stream, graph, maskJ, M2e);
    hipLaunchKernelGGL(k_pre, dim3(1536), dim3(256), 0, stream, x, xh2, W, Wht2, Wr, Wrt2);
    hipLaunchKernelGGL(k_gemm_h, dim3(1024), dim3(256), 0, stream, xh2, Wht2, hbT2,
                       wi, wj, a2, b2, M2e);
    hipLaunchKernelGGL(k_prep, dim3(128), dim3(256), 0, stream, a2, b2, M2e, ABpre, Bpre);
    hipLaunchKernelGGL(k_main, dim3(1024), dim3(256), 0, stream, xh2, hbT2, Wrt2, maskJ,
                       ABpre, Bpre, bias, out);
}